// Round 5
// baseline (2690.092 us; speedup 1.0000x reference)
//
#include <hip/hip_runtime.h>
#include <hip/hip_bf16.h>

// Problem constants (from reference)
#define Bb  32
#define Tt  12
#define Nn  5000
#define INc 2
#define Hh  128
#define HORc 12
#define Ee  80000
#define NTt (Bb*Nn)   // 160000

typedef float f4  __attribute__((ext_vector_type(4)));
typedef _Float16 h8 __attribute__((ext_vector_type(8)));
typedef _Float16 h4 __attribute__((ext_vector_type(4)));
typedef _Float16 h2 __attribute__((ext_vector_type(2)));

// per-wave LDS (halfs): hcL[32][172]  (no zL buffer -- z lives in registers)
#define HSTRIDE 172
#define WAVE_LDS (32*HSTRIDE)   // 5504 halfs = 11008 B; block = 44032 B -> 3 blocks/CU

__device__ __forceinline__ float ldf(const void* p, size_t i, int isbf){
  return isbf ? __bfloat162float(((const __hip_bfloat16*)p)[i]) : ((const float*)p)[i];
}
__device__ __forceinline__ int eidx(const int* e, int i, int is64){
  return is64 ? e[2*i] : e[i];
}
// sigmoid/tanh via hardware exp+rcp (no div sequence, no clamps needed:
// exp overflow->inf->rcp->0 and underflow->0 give the correct saturations)
__device__ __forceinline__ float sigm1(float x){
  return __builtin_amdgcn_rcpf(1.f + __expf(-x));
}
__device__ __forceinline__ float tanh1(float x){
  return 1.f - 2.f*__builtin_amdgcn_rcpf(1.f + __expf(2.f*x));
}

// ---------------- dtype detection ----------------
__global__ __launch_bounds__(256) void k_detect(const void* W2raw, const int* edge32, int* flags){
  __shared__ int cnt_bf, cnt_odd;
  if (threadIdx.x==0){ cnt_bf=0; cnt_odd=0; }
  __syncthreads();
  {
    unsigned w = ((const unsigned*)W2raw)[threadIdx.x];
    unsigned hb = (w>>8)&0x7Fu;
    if (hb>=0x34u && hb<=0x3Fu) atomicAdd(&cnt_bf,1);
  }
  if (threadIdx.x < 128){
    if (edge32[2*threadIdx.x+1] != 0) atomicAdd(&cnt_odd,1);
  }
  __syncthreads();
  if (threadIdx.x==0){
    flags[0] = (cnt_bf >= 128) ? 1 : 0;
    flags[1] = (cnt_odd == 0) ? 1 : 0;
  }
}

// ---------------- graph precompute ----------------
__global__ __launch_bounds__(256) void k_deg_cnt(const int* __restrict__ edge, int* deg, int* cnt,
                                                 const int* __restrict__ flags){
  int id = blockIdx.x*256 + threadIdx.x;
  int is64 = flags[1];
  if (id < Ee){
    atomicAdd(&deg[eidx(edge, id, is64)], 1);
    atomicAdd(&cnt[eidx(edge, Ee+id, is64)], 1);
  }
}

__global__ __launch_bounds__(256) void k_dis(const int* __restrict__ deg, float* dis){
  int id = blockIdx.x*256 + threadIdx.x;
  if (id < Nn){
    int d = deg[id];
    dis[id] = d > 0 ? rsqrtf((float)d) : 0.f;
  }
}

__global__ __launch_bounds__(1024) void k_scan(const int* __restrict__ cnt, int* rowptr){
  __shared__ int part[1024];
  int t = threadIdx.x;
  int base = t*5;
  int s = 0;
  #pragma unroll
  for (int j=0;j<5;j++){ int idx=base+j; if (idx<Nn) s += cnt[idx]; }
  part[t] = s; __syncthreads();
  for (int off=1; off<1024; off<<=1){
    int add = (t>=off) ? part[t-off] : 0;
    __syncthreads();
    part[t] += add;
    __syncthreads();
  }
  int run = (t>0) ? part[t-1] : 0;
  #pragma unroll
  for (int j=0;j<5;j++){
    int idx = base+j;
    if (idx < Nn){ rowptr[idx] = run; run += cnt[idx]; }
  }
  if (t == 1023) rowptr[Nn] = part[1023];
}

__global__ __launch_bounds__(256) void k_fill(const int* __restrict__ edge,
                                              const int* __restrict__ rowptr,
                                              int* fillc, int* csr,
                                              const int* __restrict__ flags){
  int id = blockIdx.x*256 + threadIdx.x;
  int is64 = flags[1];
  if (id < Ee){
    int d = eidx(edge, Ee+id, is64);
    int pos = atomicAdd(&fillc[d], 1);
    csr[rowptr[d] + pos] = eidx(edge, id, is64);
  }
}

// ---------------- weight precompute (element-parallel) ----------------
__global__ __launch_bounds__(128) void k_wx(
  const void* __restrict__ W1, const void* __restrict__ b1,
  const void* __restrict__ W2, const void* __restrict__ b2,
  const void* __restrict__ Wz, const void* __restrict__ bz,
  const void* __restrict__ Wr, const void* __restrict__ br,
  const void* __restrict__ Wc, const void* __restrict__ bc,
  _Float16* __restrict__ Wext, _Float16* __restrict__ Whc,
  const int* __restrict__ flags)
{
  int bid = blockIdx.x, f = threadIdx.x;
  int isbf = flags[0];
  if (bid < 640){
    int s = bid/160, k = bid - s*160;
    float v = 0.f;
    if (k < 128){
      if (s == 0)
        v = ldf(W2,(size_t)k*128+f,isbf) - ldf(W2,(size_t)(2*128+k)*128+f,isbf);
      else {
        const void* Wg = (s==1)?Wz:((s==2)?Wr:Wc);
        v = ldf(Wg,(size_t)(128+k)*128+f,isbf);
      }
    } else if (s == 0){
      v = (k==128) ? ldf(b2,f,isbf) : 0.f;
    } else if (k < 134){
      const void* Wg = (s==1)?Wz:((s==2)?Wr:Wc);
      int q = k - 128;
      float acc = 0.f;
      for (int j=0;j<128;j++) acc += ldf(W1,(size_t)q*128+j,isbf)*ldf(Wg,(size_t)j*128+f,isbf);
      v = acc;
    } else if (k == 134){
      const void* Wg = (s==1)?Wz:((s==2)?Wr:Wc);
      const void* bg = (s==1)?bz:((s==2)?br:bc);
      float acc = ldf(bg,f,isbf);
      for (int j=0;j<128;j++) acc += ldf(b1,j,isbf)*ldf(Wg,(size_t)j*128+f,isbf);
      v = acc;
    }
    Wext[(size_t)(s*128+f)*160 + k] = (_Float16)v;
  } else {
    int k = bid - 640;  // 0..255
    float v = (k < 128) ? ldf(W2,(size_t)(128+k)*128+f,isbf)
                        : 2.f*ldf(W2,(size_t)(2*128+(k-128))*128+f,isbf);
    Whc[(size_t)f*256 + k] = (_Float16)v;
  }
}

// ---------------- x propagation (all timesteps at once) ----------------
__global__ __launch_bounds__(256) void k_px1(
  const void* __restrict__ x, const float* __restrict__ dis,
  const int* __restrict__ rowptr, const int* __restrict__ csr, float* __restrict__ px1,
  const int* __restrict__ flags)
{
  int id = blockIdx.x*256 + threadIdx.x;
  int isbf = flags[0];
  if (id < Tt*Nn){
    int t = id / Nn, n = id - t*Nn;
    int e0 = rowptr[n], e1 = rowptr[n+1];
    float a0=0.f, a1=0.f;
    for (int e=e0;e<e1;e++){
      int s = csr[e]; float ds = dis[s];
      size_t xb = (size_t)(t*Nn+s)*2;
      a0 += ds*ldf(x,xb+0,isbf); a1 += ds*ldf(x,xb+1,isbf);
    }
    float dn = -dis[n];
    px1[id*2+0] = dn*a0; px1[id*2+1] = dn*a1;
  }
}

__global__ __launch_bounds__(256) void k_px2(
  const float* __restrict__ px1, const float* __restrict__ dis,
  const int* __restrict__ rowptr, const int* __restrict__ csr, float* __restrict__ px2)
{
  int id = blockIdx.x*256 + threadIdx.x;
  if (id < Tt*Nn){
    int t = id / Nn, n = id - t*Nn;
    int e0 = rowptr[n], e1 = rowptr[n+1];
    float a0=0.f, a1=0.f;
    for (int e=e0;e<e1;e++){
      int s = csr[e]; float ds = dis[s];
      const float* pp = px1 + (size_t)(t*Nn+s)*2;
      a0 += ds*pp[0]; a1 += ds*pp[1];
    }
    float dn = -dis[n];
    px2[id*2+0] = dn*a0; px2[id*2+1] = dn*a1;
  }
}

// ---------------- per-step h propagation (fp16, 4 nodes/block) ----------------
__global__ __launch_bounds__(256) void k_ph1(
  const _Float16* __restrict__ h16, const float* __restrict__ dis,
  const int* __restrict__ rowptr, const int* __restrict__ csr,
  _Float16* __restrict__ phh)
{
  int n = blockIdx.x*4 + (threadIdx.x>>6);
  int f2 = threadIdx.x & 63;
  int e0 = rowptr[n], e1 = rowptr[n+1];
  float a0=0.f, a1=0.f;
  for (int e=e0;e<e1;e++){
    int s = csr[e]; float ds = dis[s];
    h2 v = *(const h2*)(h16 + (size_t)s*128 + 2*f2);
    a0 += ds*(float)v[0]; a1 += ds*(float)v[1];
  }
  float dn = -dis[n];
  h2 o; o[0]=(_Float16)(dn*a0); o[1]=(_Float16)(dn*a1);
  *(h2*)(phh + (size_t)n*256 + 2*f2) = o;
}

__global__ __launch_bounds__(256) void k_ph2(
  const float* __restrict__ dis,
  const int* __restrict__ rowptr, const int* __restrict__ csr,
  _Float16* __restrict__ phh)
{
  int n = blockIdx.x*4 + (threadIdx.x>>6);
  int f2 = threadIdx.x & 63;
  int e0 = rowptr[n], e1 = rowptr[n+1];
  float a0=0.f, a1=0.f;
  for (int e=e0;e<e1;e++){
    int s = csr[e]; float ds = dis[s];
    h2 v = *(const h2*)(phh + (size_t)s*256 + 2*f2);
    a0 += ds*(float)v[0]; a1 += ds*(float)v[1];
  }
  float dn = -dis[n];
  h2 o; o[0]=(_Float16)(dn*a0); o[1]=(_Float16)(dn*a1);
  *(h2*)(phh + (size_t)n*256 + 128 + 2*f2) = o;
}

// ---------------- fused GRU step, MFMA ----------------
// Wave = 32 nodes (2 tiles of 16) x all 128 features. out^T: C[f][n].
// z and hc stay in registers (C-layout matches across stages); LDS only for
// the C->B layout transform of hc / r*hc. No __syncthreads anywhere.

__device__ __forceinline__ void load_b(const _Float16* hcL, h8 (&bf)[2][5], int lane){
  int n16 = lane & 15, q8 = (lane>>4)*8;
  #pragma unroll
  for (int tl=0;tl<2;tl++)
    #pragma unroll
    for (int ks=0;ks<5;ks++)
      bf[tl][ks] = *(const h8*)&hcL[(tl*16+n16)*HSTRIDE + ks*32 + q8];
}

// stage 0: hc = h@(W2[0]-W2[2]) + b2 (+ graph K-ext for nodes < Nn); keep hc in regs + LDS
__device__ __forceinline__ void st0(
  const _Float16* __restrict__ Wst, const _Float16* __restrict__ Whc,
  const _Float16* __restrict__ h16, const _Float16* __restrict__ phh,
  _Float16* __restrict__ hcL, h4 (&hcr)[16], int gbase, int lane)
{
  int n16 = lane & 15, g = lane >> 4, q8 = g*8;
  h8 zz = {0,0,0,0,0,0,0,0};
  h8 bf[2][5];
  #pragma unroll
  for (int tl=0;tl<2;tl++){
    const _Float16* hp = h16 + (size_t)(gbase + tl*16 + n16)*128 + q8;
    #pragma unroll
    for (int ks=0;ks<4;ks++) bf[tl][ks] = *(const h8*)(hp + ks*32);
    h8 e = zz;
    if (g==0) e[0] = (_Float16)1.f;   // bias slot k=128
    bf[tl][4] = e;
  }
  bool graph = (gbase < Nn);          // wave-uniform
  h8 bg[2][8];
  if (graph){
    #pragma unroll
    for (int tl=0;tl<2;tl++){
      int node = gbase + tl*16 + n16;
      int row = node < Nn ? node : 0;
      bool ok = node < Nn;
      const _Float16* pp = phh + (size_t)row*256 + q8;
      #pragma unroll
      for (int ks=0;ks<8;ks++){
        h8 v = *(const h8*)(pp + ks*32);
        bg[tl][ks] = ok ? v : zz;
      }
    }
  }
  f4 z4 = {0.f,0.f,0.f,0.f};
  #pragma unroll
  for (int fp=0; fp<4; fp++){
    f4 acc[2][2];
    #pragma unroll
    for (int tl=0;tl<2;tl++){ acc[tl][0]=z4; acc[tl][1]=z4; }
    const _Float16* Wa = Wst + (size_t)(fp*32 + n16)*160 + q8;
    #pragma unroll
    for (int ks=0; ks<5; ks++){
      h8 a0 = *(const h8*)(Wa + ks*32);
      h8 a1 = *(const h8*)(Wa + 16*160 + ks*32);
      #pragma unroll
      for (int tl=0;tl<2;tl++){
        acc[tl][0] = __builtin_amdgcn_mfma_f32_16x16x32_f16(a0, bf[tl][ks], acc[tl][0], 0,0,0);
        acc[tl][1] = __builtin_amdgcn_mfma_f32_16x16x32_f16(a1, bf[tl][ks], acc[tl][1], 0,0,0);
      }
    }
    if (graph){
      const _Float16* Wb = Whc + (size_t)(fp*32 + n16)*256 + q8;
      #pragma unroll
      for (int ks=0; ks<8; ks++){
        h8 a0 = *(const h8*)(Wb + ks*32);
        h8 a1 = *(const h8*)(Wb + 16*256 + ks*32);
        #pragma unroll
        for (int tl=0;tl<2;tl++){
          acc[tl][0] = __builtin_amdgcn_mfma_f32_16x16x32_f16(a0, bg[tl][ks], acc[tl][0], 0,0,0);
          acc[tl][1] = __builtin_amdgcn_mfma_f32_16x16x32_f16(a1, bg[tl][ks], acc[tl][1], 0,0,0);
        }
      }
    }
    #pragma unroll
    for (int tl=0;tl<2;tl++)
      #pragma unroll
      for (int hh=0;hh<2;hh++){
        int fb = fp*32 + hh*16 + g*4;
        f4 a = acc[tl][hh];
        h4 o;
        #pragma unroll
        for (int r=0;r<4;r++) o[r] = (_Float16)a[r];
        hcr[fp*4 + tl*2 + hh] = o;
        *(h4*)&hcL[(tl*16+n16)*HSTRIDE + fb] = o;
      }
  }
}

// stage 1: z = sigmoid(...) -> registers only
__device__ __forceinline__ void st_z(
  const _Float16* __restrict__ Wst, const h8 (&bf)[2][5],
  h4 (&zr)[16], int lane)
{
  int n16 = lane & 15, q8 = (lane>>4)*8;
  f4 z4 = {0.f,0.f,0.f,0.f};
  #pragma unroll
  for (int fp=0; fp<4; fp++){
    f4 acc[2][2];
    #pragma unroll
    for (int tl=0;tl<2;tl++){ acc[tl][0]=z4; acc[tl][1]=z4; }
    const _Float16* Wa = Wst + (size_t)(fp*32 + n16)*160 + q8;
    #pragma unroll
    for (int ks=0; ks<5; ks++){
      h8 a0 = *(const h8*)(Wa + ks*32);
      h8 a1 = *(const h8*)(Wa + 16*160 + ks*32);
      #pragma unroll
      for (int tl=0;tl<2;tl++){
        acc[tl][0] = __builtin_amdgcn_mfma_f32_16x16x32_f16(a0, bf[tl][ks], acc[tl][0], 0,0,0);
        acc[tl][1] = __builtin_amdgcn_mfma_f32_16x16x32_f16(a1, bf[tl][ks], acc[tl][1], 0,0,0);
      }
    }
    #pragma unroll
    for (int tl=0;tl<2;tl++)
      #pragma unroll
      for (int hh=0;hh<2;hh++){
        f4 a = acc[tl][hh];
        h4 o;
        #pragma unroll
        for (int r=0;r<4;r++) o[r] = (_Float16)sigm1(a[r]);
        zr[fp*4 + tl*2 + hh] = o;
      }
  }
}

// stage 2: r = sigmoid(...); write r*hc (regs) into hcL
__device__ __forceinline__ void st_r(
  const _Float16* __restrict__ Wst, const h8 (&bf)[2][5],
  const h4 (&hcr)[16], _Float16* __restrict__ hcL, int lane)
{
  int n16 = lane & 15, g = lane >> 4, q8 = g*8;
  f4 z4 = {0.f,0.f,0.f,0.f};
  #pragma unroll
  for (int fp=0; fp<4; fp++){
    f4 acc[2][2];
    #pragma unroll
    for (int tl=0;tl<2;tl++){ acc[tl][0]=z4; acc[tl][1]=z4; }
    const _Float16* Wa = Wst + (size_t)(fp*32 + n16)*160 + q8;
    #pragma unroll
    for (int ks=0; ks<5; ks++){
      h8 a0 = *(const h8*)(Wa + ks*32);
      h8 a1 = *(const h8*)(Wa + 16*160 + ks*32);
      #pragma unroll
      for (int tl=0;tl<2;tl++){
        acc[tl][0] = __builtin_amdgcn_mfma_f32_16x16x32_f16(a0, bf[tl][ks], acc[tl][0], 0,0,0);
        acc[tl][1] = __builtin_amdgcn_mfma_f32_16x16x32_f16(a1, bf[tl][ks], acc[tl][1], 0,0,0);
      }
    }
    #pragma unroll
    for (int tl=0;tl<2;tl++)
      #pragma unroll
      for (int hh=0;hh<2;hh++){
        int fb = fp*32 + hh*16 + g*4;
        f4 a = acc[tl][hh];
        h4 hcv = hcr[fp*4 + tl*2 + hh];
        h4 o;
        #pragma unroll
        for (int r=0;r<4;r++) o[r] = (_Float16)(sigm1(a[r]) * (float)hcv[r]);
        *(h4*)&hcL[(tl*16+n16)*HSTRIDE + fb] = o;
      }
  }
}

// stage 3: h_new = z*h_old + (1-z)*tanh(...)
__device__ __forceinline__ void st_c(
  const _Float16* __restrict__ Wst, const h8 (&bf)[2][5],
  const h4 (&zr)[16], _Float16* __restrict__ h16, int gbase, int lane)
{
  int n16 = lane & 15, g = lane >> 4, q8 = g*8;
  f4 z4 = {0.f,0.f,0.f,0.f};
  #pragma unroll
  for (int fp=0; fp<4; fp++){
    f4 acc[2][2];
    #pragma unroll
    for (int tl=0;tl<2;tl++){ acc[tl][0]=z4; acc[tl][1]=z4; }
    const _Float16* Wa = Wst + (size_t)(fp*32 + n16)*160 + q8;
    #pragma unroll
    for (int ks=0; ks<5; ks++){
      h8 a0 = *(const h8*)(Wa + ks*32);
      h8 a1 = *(const h8*)(Wa + 16*160 + ks*32);
      #pragma unroll
      for (int tl=0;tl<2;tl++){
        acc[tl][0] = __builtin_amdgcn_mfma_f32_16x16x32_f16(a0, bf[tl][ks], acc[tl][0], 0,0,0);
        acc[tl][1] = __builtin_amdgcn_mfma_f32_16x16x32_f16(a1, bf[tl][ks], acc[tl][1], 0,0,0);
      }
    }
    #pragma unroll
    for (int tl=0;tl<2;tl++)
      #pragma unroll
      for (int hh=0;hh<2;hh++){
        int fb = fp*32 + hh*16 + g*4;
        int gi = gbase + tl*16 + n16;
        f4 a = acc[tl][hh];
        h4 ho = *(const h4*)(h16 + (size_t)gi*128 + fb);
        h4 zv = zr[fp*4 + tl*2 + hh];
        h4 o;
        #pragma unroll
        for (int r=0;r<4;r++){
          float z = (float)zv[r];
          o[r] = (_Float16)(z*(float)ho[r] + (1.f - z)*tanh1(a[r]));
        }
        *(h4*)(h16 + (size_t)gi*128 + fb) = o;
      }
  }
}

__global__ __launch_bounds__(256, 3) void k_mainm(
    _Float16* __restrict__ h16, const void* __restrict__ x,
    const float* __restrict__ px1, const float* __restrict__ px2,
    const _Float16* __restrict__ phh,
    const _Float16* __restrict__ Wext, const _Float16* __restrict__ Whc,
    const int* __restrict__ flags, int t)
{
  __shared__ _Float16 smem[4*WAVE_LDS];   // 44032 B -> 3 blocks/CU
  int tid = threadIdx.x;
  int w = tid >> 6, lane = tid & 63;
  int gbase = blockIdx.x*128 + w*32;
  _Float16* hcL = smem + w*WAVE_LDS;

  // K-extension slots: hcL[n][128..134] = {x0,x1,u1a,u1b,u2a,u2b,1}, 135..159 = 0
  if (lane < 32){
    int n = lane;
    _Float16* row = hcL + n*HSTRIDE;
    for (int k=135;k<160;k++) row[k] = (_Float16)0.f;
    int isbf = flags[0];
    int i = gbase + n;
    int b = i / Nn, nn2 = i - b*Nn;
    size_t xb = ((size_t)(b*Tt + t)*Nn + nn2)*2;
    float x0 = ldf(x,xb+0,isbf), x1 = ldf(x,xb+1,isbf);
    float u1a=0.f,u1b=0.f,u2a=-x0,u2b=-x1;   // nodes >= Nn: Tx1=0, Tx2=-x
    if (i < Nn){
      u1a = px1[(t*Nn+i)*2+0]; u1b = px1[(t*Nn+i)*2+1];
      u2a = 2.f*px2[(t*Nn+i)*2+0] - x0; u2b = 2.f*px2[(t*Nn+i)*2+1] - x1;
    }
    row[128]=(_Float16)x0;  row[129]=(_Float16)x1;
    row[130]=(_Float16)u1a; row[131]=(_Float16)u1b;
    row[132]=(_Float16)u2a; row[133]=(_Float16)u2b;
    row[134]=(_Float16)1.f;
  }
  // waves fully independent; same-wave LDS ordering handled by waitcnt

  h4 hcr[16], zr[16];
  st0(Wext, Whc, h16, phh, hcL, hcr, gbase, lane);

  h8 ba[2][5];
  load_b(hcL, ba, lane);
  st_z(Wext + 1*20480, ba, zr, lane);
  st_r(Wext + 2*20480, ba, hcr, hcL, lane);

  h8 bc[2][5];
  load_b(hcL, bc, lane);
  st_c(Wext + 3*20480, bc, zr, h16, gbase, lane);
}

// ---------------- output projection ----------------
__global__ __launch_bounds__(256) void k_out(
  const _Float16* __restrict__ h16, const void* __restrict__ Wo,
  const void* __restrict__ bo, void* __restrict__ out,
  const int* __restrict__ flags)
{
  __shared__ float wol[128*HORc];
  __shared__ float wob[HORc];
  int isbf = flags[0];
  for (int idx=threadIdx.x; idx<128*HORc; idx+=256) wol[idx] = ldf(Wo, idx, isbf);
  if (threadIdx.x < HORc) wob[threadIdx.x] = ldf(bo, threadIdx.x, isbf);
  __syncthreads();

  int i = blockIdx.x*256 + threadIdx.x;
  if (i < NTt){
    float acc[HORc];
    #pragma unroll
    for (int j=0;j<HORc;j++) acc[j] = wob[j];
    const _Float16* hp = h16 + (size_t)i*128;
    for (int kb=0;kb<16;kb++){
      h8 hv = *(const h8*)(hp + kb*8);
      #pragma unroll
      for (int j=0;j<8;j++){
        float hvf = (float)hv[j];
        #pragma unroll
        for (int jj=0;jj<HORc;jj++) acc[jj] += hvf * wol[(kb*8+j)*HORc + jj];
      }
    }
    int b = i / Nn, n = i - b*Nn;
    #pragma unroll
    for (int j=0;j<HORc;j++){
      size_t oi = (size_t)(b*HORc+j)*Nn + n;
      if (isbf) ((__hip_bfloat16*)out)[oi] = __float2bfloat16(acc[j]);
      else      ((float*)out)[oi] = acc[j];
    }
  }
}

// ---------------- host ----------------
extern "C" void kernel_launch(void* const* d_in, const int* in_sizes, int n_in,
                              void* d_out, int out_size, void* d_ws, size_t ws_size,
                              hipStream_t stream) {
  (void)in_sizes; (void)n_in; (void)out_size; (void)ws_size;
  const void* x   = d_in[0];
  const int*  edge= (const int*)d_in[1];
  const void* W1  = d_in[2];
  const void* b1  = d_in[3];
  const void* W2  = d_in[4];
  const void* b2  = d_in[5];
  const void* Wz  = d_in[6];
  const void* bz  = d_in[7];
  const void* Wr  = d_in[8];
  const void* br  = d_in[9];
  const void* Wc  = d_in[10];
  const void* bc  = d_in[11];
  const void* Wo  = d_in[12];
  const void* bo  = d_in[13];

  char* ws = (char*)d_ws;
  size_t off = 0;
  auto alloc = [&](size_t bytes)->char*{
    char* p = ws + off;
    off += (bytes + 255) & ~(size_t)255;
    return p;
  };
  _Float16* h16  = (_Float16*)alloc((size_t)NTt*128*2);   // 41 MB, zeroed
  int*   deg   = (int*)  alloc(Nn*4);                     // zeroed
  int*   cnt   = (int*)  alloc(Nn*4);                     // zeroed
  int*   fillc = (int*)  alloc(Nn*4);                     // zeroed
  size_t zlen = off;
  int*   flags = (int*)  alloc(16*4);
  float* dis   = (float*)alloc(Nn*4);
  int*   rowptr= (int*)  alloc((Nn+1)*4);
  int*   csr   = (int*)  alloc(Ee*4);
  float* px1   = (float*)alloc((size_t)Tt*Nn*2*4);
  float* px2   = (float*)alloc((size_t)Tt*Nn*2*4);
  _Float16* phh  = (_Float16*)alloc((size_t)5120*256*2);  // ph1|ph2 fp16 rows (padded)
  _Float16* Wext = (_Float16*)alloc((size_t)4*128*160*2);
  _Float16* Whc  = (_Float16*)alloc((size_t)128*256*2);

  hipMemsetAsync(d_ws, 0, zlen, stream);

  k_detect <<<1,256,0,stream>>>(W2, edge, flags);
  k_deg_cnt<<<(Ee+255)/256,256,0,stream>>>(edge, deg, cnt, flags);
  k_dis    <<<(Nn+255)/256,256,0,stream>>>(deg, dis);
  k_scan   <<<1,1024,0,stream>>>(cnt, rowptr);
  k_fill   <<<(Ee+255)/256,256,0,stream>>>(edge, rowptr, fillc, csr, flags);
  k_wx     <<<896,128,0,stream>>>(W1,b1,W2,b2,Wz,bz,Wr,br,Wc,bc, Wext, Whc, flags);
  k_px1    <<<(Tt*Nn+255)/256,256,0,stream>>>(x, dis, rowptr, csr, px1, flags);
  k_px2    <<<(Tt*Nn+255)/256,256,0,stream>>>(px1, dis, rowptr, csr, px2);

  for (int t=0; t<Tt; ++t){
    k_ph1  <<<Nn/4,256,0,stream>>>(h16, dis, rowptr, csr, phh);
    k_ph2  <<<Nn/4,256,0,stream>>>(dis, rowptr, csr, phh);
    k_mainm<<<NTt/128,256,0,stream>>>(h16, x, px1, px2, phh, Wext, Whc, flags, t);
  }

  k_out<<<(NTt+255)/256,256,0,stream>>>(h16, Wo, bo, d_out, flags);
}

// Round 6
// 1430.884 us; speedup vs baseline: 1.8800x; 1.8800x over previous
//
#include <hip/hip_runtime.h>
#include <hip/hip_bf16.h>

// Problem constants (from reference)
#define Bb  32
#define Tt  12
#define Nn  5000
#define INc 2
#define Hh  128
#define HORc 12
#define Ee  80000
#define NTt (Bb*Nn)   // 160000

typedef float f4  __attribute__((ext_vector_type(4)));
typedef _Float16 h8 __attribute__((ext_vector_type(8)));
typedef _Float16 h4 __attribute__((ext_vector_type(4)));
typedef _Float16 h2 __attribute__((ext_vector_type(2)));

// per-wave LDS (halfs): hcL[32][172] | zL[32][136]   (round-4 proven layout)
#define HSTRIDE 172
#define ZSTRIDE 136
#define WAVE_LDS (32*HSTRIDE + 32*ZSTRIDE)   // 9856 halfs = 19712 B; block 78848 B -> 2 blocks/CU

__device__ __forceinline__ float ldf(const void* p, size_t i, int isbf){
  return isbf ? __bfloat162float(((const __hip_bfloat16*)p)[i]) : ((const float*)p)[i];
}
__device__ __forceinline__ int eidx(const int* e, int i, int is64){
  return is64 ? e[2*i] : e[i];
}
// sigmoid/tanh via hardware exp+rcp: ~4 VALU insts vs ~14 for the div sequence.
// No clamps needed: exp overflow->inf->rcp->0 / underflow->0 give correct saturation.
__device__ __forceinline__ float sigm1(float x){
  return __builtin_amdgcn_rcpf(1.f + __expf(-x));
}
__device__ __forceinline__ float tanh1(float x){
  return 1.f - 2.f*__builtin_amdgcn_rcpf(1.f + __expf(2.f*x));
}

// ---------------- dtype detection ----------------
__global__ __launch_bounds__(256) void k_detect(const void* W2raw, const int* edge32, int* flags){
  __shared__ int cnt_bf, cnt_odd;
  if (threadIdx.x==0){ cnt_bf=0; cnt_odd=0; }
  __syncthreads();
  {
    unsigned w = ((const unsigned*)W2raw)[threadIdx.x];
    unsigned hb = (w>>8)&0x7Fu;
    if (hb>=0x34u && hb<=0x3Fu) atomicAdd(&cnt_bf,1);
  }
  if (threadIdx.x < 128){
    if (edge32[2*threadIdx.x+1] != 0) atomicAdd(&cnt_odd,1);
  }
  __syncthreads();
  if (threadIdx.x==0){
    flags[0] = (cnt_bf >= 128) ? 1 : 0;
    flags[1] = (cnt_odd == 0) ? 1 : 0;
  }
}

// ---------------- graph precompute ----------------
__global__ __launch_bounds__(256) void k_deg_cnt(const int* __restrict__ edge, int* deg, int* cnt,
                                                 const int* __restrict__ flags){
  int id = blockIdx.x*256 + threadIdx.x;
  int is64 = flags[1];
  if (id < Ee){
    atomicAdd(&deg[eidx(edge, id, is64)], 1);
    atomicAdd(&cnt[eidx(edge, Ee+id, is64)], 1);
  }
}

__global__ __launch_bounds__(256) void k_dis(const int* __restrict__ deg, float* dis){
  int id = blockIdx.x*256 + threadIdx.x;
  if (id < Nn){
    int d = deg[id];
    dis[id] = d > 0 ? rsqrtf((float)d) : 0.f;
  }
}

__global__ __launch_bounds__(1024) void k_scan(const int* __restrict__ cnt, int* rowptr){
  __shared__ int part[1024];
  int t = threadIdx.x;
  int base = t*5;
  int s = 0;
  #pragma unroll
  for (int j=0;j<5;j++){ int idx=base+j; if (idx<Nn) s += cnt[idx]; }
  part[t] = s; __syncthreads();
  for (int off=1; off<1024; off<<=1){
    int add = (t>=off) ? part[t-off] : 0;
    __syncthreads();
    part[t] += add;
    __syncthreads();
  }
  int run = (t>0) ? part[t-1] : 0;
  #pragma unroll
  for (int j=0;j<5;j++){
    int idx = base+j;
    if (idx < Nn){ rowptr[idx] = run; run += cnt[idx]; }
  }
  if (t == 1023) rowptr[Nn] = part[1023];
}

__global__ __launch_bounds__(256) void k_fill(const int* __restrict__ edge,
                                              const int* __restrict__ rowptr,
                                              int* fillc, int* csr,
                                              const int* __restrict__ flags){
  int id = blockIdx.x*256 + threadIdx.x;
  int is64 = flags[1];
  if (id < Ee){
    int d = eidx(edge, Ee+id, is64);
    int pos = atomicAdd(&fillc[d], 1);
    csr[rowptr[d] + pos] = eidx(edge, id, is64);
  }
}

// ---------------- weight precompute (element-parallel) ----------------
__global__ __launch_bounds__(128) void k_wx(
  const void* __restrict__ W1, const void* __restrict__ b1,
  const void* __restrict__ W2, const void* __restrict__ b2,
  const void* __restrict__ Wz, const void* __restrict__ bz,
  const void* __restrict__ Wr, const void* __restrict__ br,
  const void* __restrict__ Wc, const void* __restrict__ bc,
  _Float16* __restrict__ Wext, _Float16* __restrict__ Whc,
  const int* __restrict__ flags)
{
  int bid = blockIdx.x, f = threadIdx.x;
  int isbf = flags[0];
  if (bid < 640){
    int s = bid/160, k = bid - s*160;
    float v = 0.f;
    if (k < 128){
      if (s == 0)
        v = ldf(W2,(size_t)k*128+f,isbf) - ldf(W2,(size_t)(2*128+k)*128+f,isbf);
      else {
        const void* Wg = (s==1)?Wz:((s==2)?Wr:Wc);
        v = ldf(Wg,(size_t)(128+k)*128+f,isbf);
      }
    } else if (s == 0){
      v = (k==128) ? ldf(b2,f,isbf) : 0.f;
    } else if (k < 134){
      const void* Wg = (s==1)?Wz:((s==2)?Wr:Wc);
      int q = k - 128;
      float acc = 0.f;
      for (int j=0;j<128;j++) acc += ldf(W1,(size_t)q*128+j,isbf)*ldf(Wg,(size_t)j*128+f,isbf);
      v = acc;
    } else if (k == 134){
      const void* Wg = (s==1)?Wz:((s==2)?Wr:Wc);
      const void* bg = (s==1)?bz:((s==2)?br:bc);
      float acc = ldf(bg,f,isbf);
      for (int j=0;j<128;j++) acc += ldf(b1,j,isbf)*ldf(Wg,(size_t)j*128+f,isbf);
      v = acc;
    }
    Wext[(size_t)(s*128+f)*160 + k] = (_Float16)v;
  } else {
    int k = bid - 640;  // 0..255
    float v = (k < 128) ? ldf(W2,(size_t)(128+k)*128+f,isbf)
                        : 2.f*ldf(W2,(size_t)(2*128+(k-128))*128+f,isbf);
    Whc[(size_t)f*256 + k] = (_Float16)v;
  }
}

// ---------------- x propagation (all timesteps at once) ----------------
__global__ __launch_bounds__(256) void k_px1(
  const void* __restrict__ x, const float* __restrict__ dis,
  const int* __restrict__ rowptr, const int* __restrict__ csr, float* __restrict__ px1,
  const int* __restrict__ flags)
{
  int id = blockIdx.x*256 + threadIdx.x;
  int isbf = flags[0];
  if (id < Tt*Nn){
    int t = id / Nn, n = id - t*Nn;
    int e0 = rowptr[n], e1 = rowptr[n+1];
    float a0=0.f, a1=0.f;
    for (int e=e0;e<e1;e++){
      int s = csr[e]; float ds = dis[s];
      size_t xb = (size_t)(t*Nn+s)*2;
      a0 += ds*ldf(x,xb+0,isbf); a1 += ds*ldf(x,xb+1,isbf);
    }
    float dn = -dis[n];
    px1[id*2+0] = dn*a0; px1[id*2+1] = dn*a1;
  }
}

__global__ __launch_bounds__(256) void k_px2(
  const float* __restrict__ px1, const float* __restrict__ dis,
  const int* __restrict__ rowptr, const int* __restrict__ csr, float* __restrict__ px2)
{
  int id = blockIdx.x*256 + threadIdx.x;
  if (id < Tt*Nn){
    int t = id / Nn, n = id - t*Nn;
    int e0 = rowptr[n], e1 = rowptr[n+1];
    float a0=0.f, a1=0.f;
    for (int e=e0;e<e1;e++){
      int s = csr[e]; float ds = dis[s];
      const float* pp = px1 + (size_t)(t*Nn+s)*2;
      a0 += ds*pp[0]; a1 += ds*pp[1];
    }
    float dn = -dis[n];
    px2[id*2+0] = dn*a0; px2[id*2+1] = dn*a1;
  }
}

// ---------------- per-step h propagation (fp16, 4 nodes/block) ----------------
__global__ __launch_bounds__(256) void k_ph1(
  const _Float16* __restrict__ h16, const float* __restrict__ dis,
  const int* __restrict__ rowptr, const int* __restrict__ csr,
  _Float16* __restrict__ phh)
{
  int n = blockIdx.x*4 + (threadIdx.x>>6);
  int f2 = threadIdx.x & 63;
  int e0 = rowptr[n], e1 = rowptr[n+1];
  float a0=0.f, a1=0.f;
  for (int e=e0;e<e1;e++){
    int s = csr[e]; float ds = dis[s];
    h2 v = *(const h2*)(h16 + (size_t)s*128 + 2*f2);
    a0 += ds*(float)v[0]; a1 += ds*(float)v[1];
  }
  float dn = -dis[n];
  h2 o; o[0]=(_Float16)(dn*a0); o[1]=(_Float16)(dn*a1);
  *(h2*)(phh + (size_t)n*256 + 2*f2) = o;
}

__global__ __launch_bounds__(256) void k_ph2(
  const float* __restrict__ dis,
  const int* __restrict__ rowptr, const int* __restrict__ csr,
  _Float16* __restrict__ phh)
{
  int n = blockIdx.x*4 + (threadIdx.x>>6);
  int f2 = threadIdx.x & 63;
  int e0 = rowptr[n], e1 = rowptr[n+1];
  float a0=0.f, a1=0.f;
  for (int e=e0;e<e1;e++){
    int s = csr[e]; float ds = dis[s];
    h2 v = *(const h2*)(phh + (size_t)s*256 + 2*f2);
    a0 += ds*(float)v[0]; a1 += ds*(float)v[1];
  }
  float dn = -dis[n];
  h2 o; o[0]=(_Float16)(dn*a0); o[1]=(_Float16)(dn*a1);
  *(h2*)(phh + (size_t)n*256 + 128 + 2*f2) = o;
}

// ---------------- fused GRU step, MFMA (round-4 structure) ----------------
// Wave = 32 nodes (2 tiles of 16) x all 128 features. out^T: C[f][n].
// A = Wext/Whc rows from global (L1/L2-hot); B = activations (global h16 / per-wave LDS).
// No __syncthreads anywhere.

__device__ __forceinline__ void load_b(const _Float16* hcL, h8 (&bf)[2][5], int lane){
  int n16 = lane & 15, q8 = (lane>>4)*8;
  #pragma unroll
  for (int tl=0;tl<2;tl++)
    #pragma unroll
    for (int ks=0;ks<5;ks++)
      bf[tl][ks] = *(const h8*)&hcL[(tl*16+n16)*HSTRIDE + ks*32 + q8];
}

// stage 0: hc = h@(W2[0]-W2[2]) + b2 (+ graph K-ext for nodes < Nn)
__device__ __forceinline__ void st0(
  const _Float16* __restrict__ Wst, const _Float16* __restrict__ Whc,
  const _Float16* __restrict__ h16, const _Float16* __restrict__ phh,
  _Float16* __restrict__ hcL, int gbase, int lane)
{
  int n16 = lane & 15, g = lane >> 4, q8 = g*8;
  h8 zz = {0,0,0,0,0,0,0,0};
  h8 bf[2][5];
  #pragma unroll
  for (int tl=0;tl<2;tl++){
    const _Float16* hp = h16 + (size_t)(gbase + tl*16 + n16)*128 + q8;
    #pragma unroll
    for (int ks=0;ks<4;ks++) bf[tl][ks] = *(const h8*)(hp + ks*32);
    h8 e = zz;
    if (g==0) e[0] = (_Float16)1.f;   // bias slot k=128
    bf[tl][4] = e;
  }
  bool graph = (gbase < Nn);          // wave-uniform
  h8 bg[2][8];
  if (graph){
    #pragma unroll
    for (int tl=0;tl<2;tl++){
      int node = gbase + tl*16 + n16;
      int row = node < Nn ? node : 0;
      bool ok = node < Nn;
      const _Float16* pp = phh + (size_t)row*256 + q8;
      #pragma unroll
      for (int ks=0;ks<8;ks++){
        h8 v = *(const h8*)(pp + ks*32);
        bg[tl][ks] = ok ? v : zz;
      }
    }
  }
  f4 z4 = {0.f,0.f,0.f,0.f};
  #pragma unroll
  for (int fp=0; fp<4; fp++){
    f4 acc[2][2];
    #pragma unroll
    for (int tl=0;tl<2;tl++){ acc[tl][0]=z4; acc[tl][1]=z4; }
    const _Float16* Wa = Wst + (size_t)(fp*32 + n16)*160 + q8;
    #pragma unroll
    for (int ks=0; ks<5; ks++){
      h8 a0 = *(const h8*)(Wa + ks*32);
      h8 a1 = *(const h8*)(Wa + 16*160 + ks*32);
      #pragma unroll
      for (int tl=0;tl<2;tl++){
        acc[tl][0] = __builtin_amdgcn_mfma_f32_16x16x32_f16(a0, bf[tl][ks], acc[tl][0], 0,0,0);
        acc[tl][1] = __builtin_amdgcn_mfma_f32_16x16x32_f16(a1, bf[tl][ks], acc[tl][1], 0,0,0);
      }
    }
    if (graph){
      const _Float16* Wb = Whc + (size_t)(fp*32 + n16)*256 + q8;
      #pragma unroll
      for (int ks=0; ks<8; ks++){
        h8 a0 = *(const h8*)(Wb + ks*32);
        h8 a1 = *(const h8*)(Wb + 16*256 + ks*32);
        #pragma unroll
        for (int tl=0;tl<2;tl++){
          acc[tl][0] = __builtin_amdgcn_mfma_f32_16x16x32_f16(a0, bg[tl][ks], acc[tl][0], 0,0,0);
          acc[tl][1] = __builtin_amdgcn_mfma_f32_16x16x32_f16(a1, bg[tl][ks], acc[tl][1], 0,0,0);
        }
      }
    }
    #pragma unroll
    for (int tl=0;tl<2;tl++)
      #pragma unroll
      for (int hh=0;hh<2;hh++){
        int fb = fp*32 + hh*16 + g*4;
        f4 a = acc[tl][hh];
        h4 o;
        #pragma unroll
        for (int r=0;r<4;r++) o[r] = (_Float16)a[r];
        *(h4*)&hcL[(tl*16+n16)*HSTRIDE + fb] = o;
      }
  }
}

// stages 1(z->zL) / 2(r, overwrite hcL with r*hc) / 3(c + blend, write h16)
template<int S>
__device__ __forceinline__ void mm_stage(
  const _Float16* __restrict__ Wst, const h8 (&bf)[2][5],
  _Float16* __restrict__ hcL, _Float16* __restrict__ zL,
  _Float16* __restrict__ h16, int gbase, int lane)
{
  int n16 = lane & 15, g = lane >> 4, q8 = g*8;
  f4 z4 = {0.f,0.f,0.f,0.f};
  #pragma unroll
  for (int fp=0; fp<4; fp++){
    f4 acc[2][2];
    #pragma unroll
    for (int tl=0;tl<2;tl++){ acc[tl][0]=z4; acc[tl][1]=z4; }
    const _Float16* Wa = Wst + (size_t)(fp*32 + n16)*160 + q8;
    #pragma unroll
    for (int ks=0; ks<5; ks++){
      h8 a0 = *(const h8*)(Wa + ks*32);
      h8 a1 = *(const h8*)(Wa + 16*160 + ks*32);
      #pragma unroll
      for (int tl=0;tl<2;tl++){
        acc[tl][0] = __builtin_amdgcn_mfma_f32_16x16x32_f16(a0, bf[tl][ks], acc[tl][0], 0,0,0);
        acc[tl][1] = __builtin_amdgcn_mfma_f32_16x16x32_f16(a1, bf[tl][ks], acc[tl][1], 0,0,0);
      }
    }
    #pragma unroll
    for (int tl=0;tl<2;tl++)
      #pragma unroll
      for (int hh=0;hh<2;hh++){
        int fb = fp*32 + hh*16 + g*4;
        int nn = tl*16 + n16;
        f4 a = acc[tl][hh];
        if (S == 1){
          h4 o;
          #pragma unroll
          for (int r=0;r<4;r++) o[r] = (_Float16)sigm1(a[r]);
          *(h4*)&zL[nn*ZSTRIDE + fb] = o;
        } else if (S == 2){
          h4 hcv = *(const h4*)&hcL[nn*HSTRIDE + fb];
          h4 o;
          #pragma unroll
          for (int r=0;r<4;r++) o[r] = (_Float16)(sigm1(a[r]) * (float)hcv[r]);
          *(h4*)&hcL[nn*HSTRIDE + fb] = o;
        } else {
          int gi = gbase + nn;
          h4 ho = *(const h4*)(h16 + (size_t)gi*128 + fb);
          h4 zv = *(const h4*)&zL[nn*ZSTRIDE + fb];
          h4 o;
          #pragma unroll
          for (int r=0;r<4;r++){
            float z = (float)zv[r];
            o[r] = (_Float16)(z*(float)ho[r] + (1.f - z)*tanh1(a[r]));
          }
          *(h4*)(h16 + (size_t)gi*128 + fb) = o;
        }
      }
  }
}

__global__ __launch_bounds__(256, 2) void k_mainm(
    _Float16* __restrict__ h16, const void* __restrict__ x,
    const float* __restrict__ px1, const float* __restrict__ px2,
    const _Float16* __restrict__ phh,
    const _Float16* __restrict__ Wext, const _Float16* __restrict__ Whc,
    const int* __restrict__ flags, int t)
{
  __shared__ _Float16 smem[4*WAVE_LDS];   // 78848 B -> 2 blocks/CU
  int tid = threadIdx.x;
  int w = tid >> 6, lane = tid & 63;
  int gbase = blockIdx.x*128 + w*32;
  _Float16* hcL = smem + w*WAVE_LDS;
  _Float16* zL  = hcL + 32*HSTRIDE;

  // K-extension slots: hcL[n][128..134] = {x0,x1,u1a,u1b,u2a,u2b,1}, 135..159 = 0
  if (lane < 32){
    int n = lane;
    _Float16* row = hcL + n*HSTRIDE;
    for (int k=135;k<160;k++) row[k] = (_Float16)0.f;
    int isbf = flags[0];
    int i = gbase + n;
    int b = i / Nn, nn2 = i - b*Nn;
    size_t xb = ((size_t)(b*Tt + t)*Nn + nn2)*2;
    float x0 = ldf(x,xb+0,isbf), x1 = ldf(x,xb+1,isbf);
    float u1a=0.f,u1b=0.f,u2a=-x0,u2b=-x1;   // nodes >= Nn: Tx1=0, Tx2=-x
    if (i < Nn){
      u1a = px1[(t*Nn+i)*2+0]; u1b = px1[(t*Nn+i)*2+1];
      u2a = 2.f*px2[(t*Nn+i)*2+0] - x0; u2b = 2.f*px2[(t*Nn+i)*2+1] - x1;
    }
    row[128]=(_Float16)x0;  row[129]=(_Float16)x1;
    row[130]=(_Float16)u1a; row[131]=(_Float16)u1b;
    row[132]=(_Float16)u2a; row[133]=(_Float16)u2b;
    row[134]=(_Float16)1.f;
  }
  // waves fully independent; same-wave LDS ordering handled by waitcnt

  st0(Wext, Whc, h16, phh, hcL, gbase, lane);

  h8 ba[2][5];
  load_b(hcL, ba, lane);
  mm_stage<1>(Wext + 1*20480, ba, hcL, zL, h16, gbase, lane);
  mm_stage<2>(Wext + 2*20480, ba, hcL, zL, h16, gbase, lane);

  h8 bc[2][5];
  load_b(hcL, bc, lane);
  mm_stage<3>(Wext + 3*20480, bc, hcL, zL, h16, gbase, lane);
}

// ---------------- output projection ----------------
__global__ __launch_bounds__(256) void k_out(
  const _Float16* __restrict__ h16, const void* __restrict__ Wo,
  const void* __restrict__ bo, void* __restrict__ out,
  const int* __restrict__ flags)
{
  __shared__ float wol[128*HORc];
  __shared__ float wob[HORc];
  int isbf = flags[0];
  for (int idx=threadIdx.x; idx<128*HORc; idx+=256) wol[idx] = ldf(Wo, idx, isbf);
  if (threadIdx.x < HORc) wob[threadIdx.x] = ldf(bo, threadIdx.x, isbf);
  __syncthreads();

  int i = blockIdx.x*256 + threadIdx.x;
  if (i < NTt){
    float acc[HORc];
    #pragma unroll
    for (int j=0;j<HORc;j++) acc[j] = wob[j];
    const _Float16* hp = h16 + (size_t)i*128;
    for (int kb=0;kb<16;kb++){
      h8 hv = *(const h8*)(hp + kb*8);
      #pragma unroll
      for (int j=0;j<8;j++){
        float hvf = (float)hv[j];
        #pragma unroll
        for (int jj=0;jj<HORc;jj++) acc[jj] += hvf * wol[(kb*8+j)*HORc + jj];
      }
    }
    int b = i / Nn, n = i - b*Nn;
    #pragma unroll
    for (int j=0;j<HORc;j++){
      size_t oi = (size_t)(b*HORc+j)*Nn + n;
      if (isbf) ((__hip_bfloat16*)out)[oi] = __float2bfloat16(acc[j]);
      else      ((float*)out)[oi] = acc[j];
    }
  }
}

// ---------------- host ----------------
extern "C" void kernel_launch(void* const* d_in, const int* in_sizes, int n_in,
                              void* d_out, int out_size, void* d_ws, size_t ws_size,
                              hipStream_t stream) {
  (void)in_sizes; (void)n_in; (void)out_size; (void)ws_size;
  const void* x   = d_in[0];
  const int*  edge= (const int*)d_in[1];
  const void* W1  = d_in[2];
  const void* b1  = d_in[3];
  const void* W2  = d_in[4];
  const void* b2  = d_in[5];
  const void* Wz  = d_in[6];
  const void* bz  = d_in[7];
  const void* Wr  = d_in[8];
  const void* br  = d_in[9];
  const void* Wc  = d_in[10];
  const void* bc  = d_in[11];
  const void* Wo  = d_in[12];
  const void* bo  = d_in[13];

  char* ws = (char*)d_ws;
  size_t off = 0;
  auto alloc = [&](size_t bytes)->char*{
    char* p = ws + off;
    off += (bytes + 255) & ~(size_t)255;
    return p;
  };
  _Float16* h16  = (_Float16*)alloc((size_t)NTt*128*2);   // 41 MB, zeroed
  int*   deg   = (int*)  alloc(Nn*4);                     // zeroed
  int*   cnt   = (int*)  alloc(Nn*4);                     // zeroed
  int*   fillc = (int*)  alloc(Nn*4);                     // zeroed
  size_t zlen = off;
  int*   flags = (int*)  alloc(16*4);
  float* dis   = (float*)alloc(Nn*4);
  int*   rowptr= (int*)  alloc((Nn+1)*4);
  int*   csr   = (int*)  alloc(Ee*4);
  float* px1   = (float*)alloc((size_t)Tt*Nn*2*4);
  float* px2   = (float*)alloc((size_t)Tt*Nn*2*4);
  _Float16* phh  = (_Float16*)alloc((size_t)5120*256*2);  // ph1|ph2 fp16 rows (padded)
  _Float16* Wext = (_Float16*)alloc((size_t)4*128*160*2);
  _Float16* Whc  = (_Float16*)alloc((size_t)128*256*2);

  hipMemsetAsync(d_ws, 0, zlen, stream);

  k_detect <<<1,256,0,stream>>>(W2, edge, flags);
  k_deg_cnt<<<(Ee+255)/256,256,0,stream>>>(edge, deg, cnt, flags);
  k_dis    <<<(Nn+255)/256,256,0,stream>>>(deg, dis);
  k_scan   <<<1,1024,0,stream>>>(cnt, rowptr);
  k_fill   <<<(Ee+255)/256,256,0,stream>>>(edge, rowptr, fillc, csr, flags);
  k_wx     <<<896,128,0,stream>>>(W1,b1,W2,b2,Wz,bz,Wr,br,Wc,bc, Wext, Whc, flags);
  k_px1    <<<(Tt*Nn+255)/256,256,0,stream>>>(x, dis, rowptr, csr, px1, flags);
  k_px2    <<<(Tt*Nn+255)/256,256,0,stream>>>(px1, dis, rowptr, csr, px2);

  for (int t=0; t<Tt; ++t){
    k_ph1  <<<Nn/4,256,0,stream>>>(h16, dis, rowptr, csr, phh);
    k_ph2  <<<Nn/4,256,0,stream>>>(dis, rowptr, csr, phh);
    k_mainm<<<NTt/128,256,0,stream>>>(h16, x, px1, px2, phh, Wext, Whc, flags, t);
  }

  k_out<<<(NTt+255)/256,256,0,stream>>>(h16, Wo, bo, d_out, flags);
}